// Round 18
// baseline (139.325 us; speedup 1.0000x reference)
//
#include <hip/hip_runtime.h>
#include <stdint.h>

#define S_LEN 4096
#define HQ 32
#define HKV 8
#define DD 128
#define QBLK 128
#define KVROW (HKV * DD)

typedef __attribute__((ext_vector_type(8)))  __bf16 bf16x8;
typedef __attribute__((ext_vector_type(2)))  __bf16 bf16x2;
typedef __attribute__((ext_vector_type(4)))  float  f32x4;
typedef __attribute__((ext_vector_type(2)))  unsigned int u32x2;
typedef __attribute__((ext_vector_type(4)))  unsigned int u32x4;

__device__ __forceinline__ unsigned int pk2(float lo, float hi2) {
  bf16x2 t = {(__bf16)lo, (__bf16)hi2};
  return __builtin_bit_cast(unsigned int, t);
}
__device__ __forceinline__ bf16x8 mk8(unsigned int w0, unsigned int w1,
                                      unsigned int w2, unsigned int w3) {
  u32x4 u = {w0, w1, w2, w3};
  return __builtin_bit_cast(bf16x8, u);
}

// V swizzle, 64-byte XOR window (V rows are 320 B).
#define SWZV(d) ((((d) & 7) ^ (((d) >> 4) & 7)) << 3)

// r18 = r17 ring + fully loop-carried prefetch:
//  - Q for phase j+1 issued inside phase j (top-of-phase convert frees regs)
//  - ik/iv (ring +32 keys) carried ONE FULL PHASE ahead -> slide-write never
//    waits on vmcnt
//  - slide moved to right after PAIR 0: written slots (2j,2j+1 mod 10) are
//    only read at pp=0 (cc+tt in {0,1}); pairs 1-4 overlap the write
//  - setprio removed (T5: null outside phase-split schedules, m190)
__global__ __launch_bounds__(512, 4)
void swa_fwd(const float* __restrict__ Qg, const float* __restrict__ Kg,
             const float* __restrict__ Vg, float* __restrict__ Og) {
  __shared__ __align__(16) unsigned char Kl[40960];  // ring [c:160][d:128] bf16
  __shared__ __align__(16) unsigned char Vl[40960];  // ring V^T [d:128][c:160]

  const int nwg  = gridDim.x;
  const int bid0 = blockIdx.x;
  const int bid  = (bid0 & 7) * (nwg >> 3) + (bid0 >> 3);

  const int n    = bid & 31;
  const int hkv  = (bid >> 5) & 7;
  const int b    = bid >> 8;
  const int tid  = threadIdx.x;
  const int lane = tid & 63;
  const int wv   = tid >> 6;          // 0..7
  const int g    = lane >> 4;
  const int l15  = lane & 15;

  const int cc = wv & 1;
  const int h  = hkv * 4 + (wv >> 1);

  const int c0 = tid >> 5;            // staging row base 0..15
  const int dc = tid & 31;
  const size_t kvoff = hkv * DD + dc * 4;
  const int kbase0 = (n - 1) * QBLK;

  // ---- initial fill: ring rows 0..159 = keys kbase0..kbase0+159 ----
  #pragma unroll
  for (int i = 0; i < 10; ++i) {
    const int c = c0 + i * 16;
    int tk = kbase0 + c;
    tk = tk > 0 ? tk : 0;             // n==0 left pad; garbage lands in dead tiles
    const size_t base = (size_t)(b * S_LEN + tk) * KVROW + kvoff;
    const f32x4 xk = *(const f32x4*)(Kg + base);
    const f32x4 xv = *(const f32x4*)(Vg + base);
    u32x2 kw = { pk2(xk[0], xk[1]), pk2(xk[2], xk[3]) };
    *(u32x2*)(&Kl[c * 256 + ((dc * 8) ^ (c0 << 4))]) = kw;
    #pragma unroll
    for (int j4 = 0; j4 < 4; ++j4) {
      const int d = dc * 4 + j4;
      *(unsigned short*)(&Vl[d * 320 + ((c * 2) ^ SWZV(d))]) =
          __builtin_bit_cast(unsigned short, (__bf16)xv[j4]);
    }
  }

  // ---- preload Q(phase 0) and ik/iv (gt 10,11 -> written at phase 0) ----
  f32x4 qa[4], qb[4];
  {
    const float* qp = Qg + (size_t)(b * S_LEN + n * QBLK + cc * 16 + l15) * (HQ * DD)
                      + h * DD + g * 8;
    #pragma unroll
    for (int d4 = 0; d4 < 4; ++d4) {
      qa[d4] = *(const f32x4*)(qp + d4 * 32);
      qb[d4] = *(const f32x4*)(qp + d4 * 32 + 4);
    }
  }
  f32x4 ik[2], iv[2];
  #pragma unroll
  for (int ii = 0; ii < 2; ++ii) {    // keys >= 32 always -> no clamp
    const int tk = kbase0 + 160 + c0 + 16 * ii;
    const size_t base = (size_t)(b * S_LEN + tk) * KVROW + kvoff;
    ik[ii] = *(const f32x4*)(Kg + base);
    iv[ii] = *(const f32x4*)(Vg + base);
  }
  __syncthreads();

  const float SC = 0.08838834764831845f * 1.44269504088896340f; // 1/sqrt(128)*log2e

  #pragma unroll 1
  for (int j = 0; j < 4; ++j) {
    const int qrow = n * QBLK + 32 * j + cc * 16 + l15;

    // convert this phase's Q (frees qa/qb for the j+1 prefetch)
    bf16x8 qf[4];
    #pragma unroll
    for (int d4 = 0; d4 < 4; ++d4)
      qf[d4] = mk8(pk2(qa[d4][0], qa[d4][1]), pk2(qa[d4][2], qa[d4][3]),
                   pk2(qb[d4][0], qb[d4][1]), pk2(qb[d4][2], qb[d4][3]));

    f32x4 o[8];
    #pragma unroll
    for (int dt = 0; dt < 8; ++dt) o[dt] = (f32x4){0.f, 0.f, 0.f, 0.f};
    float ls = 0.f;

    const int bt = 2 * j + cc;

#define PAIR_BODY(pp)                                                         \
    {                                                                         \
      const int tt0 = 2 * (pp), tt1 = 2 * (pp) + 1;                           \
      if (!(n == 0 && bt + tt1 < 8)) {                                        \
        unsigned int w0 = 0, w1 = 0, w2 = 0, w3 = 0;                          \
        int rt0 = bt + tt0; rt0 = (rt0 >= 10) ? rt0 - 10 : rt0;               \
        int rt1 = bt + tt1; rt1 = (rt1 >= 10) ? rt1 - 10 : rt1;               \
        if (!(n == 0 && bt + tt0 < 8)) {                                      \
          const int c = rt0 * 16 + l15;                                       \
          f32x4 acc = {0.f, 0.f, 0.f, 0.f};                                   \
          _Pragma("unroll")                                                   \
          for (int dcc = 0; dcc < 4; ++dcc) {                                 \
            const bf16x8 kf = *(const bf16x8*)(                               \
                &Kl[c * 256 + ((dcc * 64 + g * 16) ^ (l15 << 4))]);           \
            acc = __builtin_amdgcn_mfma_f32_16x16x32_bf16(kf, qf[dcc], acc,   \
                                                          0, 0, 0);           \
          }                                                                   \
          float p[4];                                                         \
          _Pragma("unroll")                                                   \
          for (int r = 0; r < 4; ++r) {                                       \
            const int g4r = g * 4 + r;                                        \
            const float e = __builtin_amdgcn_exp2f(acc[r] * SC);              \
            bool valid = true;                                                \
            if ((pp) == 0) valid = (g4r > l15);                               \
            if ((pp) == 4) valid = (g4r <= l15);                              \
            p[r] = valid ? e : 0.f;                                           \
            ls += p[r];                                                       \
          }                                                                   \
          w0 = pk2(p[0], p[1]);                                               \
          w1 = pk2(p[2], p[3]);                                               \
        }                                                                     \
        if ((pp) < 4 && !(n == 0 && bt + tt1 < 8)) {                          \
          const int c = rt1 * 16 + l15;                                       \
          f32x4 acc = {0.f, 0.f, 0.f, 0.f};                                   \
          _Pragma("unroll")                                                   \
          for (int dcc = 0; dcc < 4; ++dcc) {                                 \
            const bf16x8 kf = *(const bf16x8*)(                               \
                &Kl[c * 256 + ((dcc * 64 + g * 16) ^ (l15 << 4))]);           \
            acc = __builtin_amdgcn_mfma_f32_16x16x32_bf16(kf, qf[dcc], acc,   \
                                                          0, 0, 0);           \
          }                                                                   \
          float p0 = __builtin_amdgcn_exp2f(acc[0] * SC);                     \
          float p1 = __builtin_amdgcn_exp2f(acc[1] * SC);                     \
          float p2 = __builtin_amdgcn_exp2f(acc[2] * SC);                     \
          float p3 = __builtin_amdgcn_exp2f(acc[3] * SC);                     \
          ls += p0 + p1 + p2 + p3;                                            \
          w2 = pk2(p0, p1);                                                   \
          w3 = pk2(p2, p3);                                                   \
        }                                                                     \
        const bf16x8 pf = mk8(w0, w1, w2, w3);                                \
        const int ck0 = (rt0 * 16 + g * 4) * 2;                               \
        const int ck1 = ((pp) < 4) ? (rt1 * 16 + g * 4) * 2 : ck0;            \
        _Pragma("unroll")                                                     \
        for (int dt = 0; dt < 8; ++dt) {                                      \
          const int d  = dt * 16 + l15;                                       \
          const int rb = d * 320;                                             \
          const int sz = SWZV(d);                                             \
          const u32x2 a0 = *(const u32x2*)(&Vl[rb + (ck0 ^ sz)]);             \
          const u32x2 a1 = *(const u32x2*)(&Vl[rb + (ck1 ^ sz)]);             \
          const bf16x8 vf = mk8(a0[0], a0[1], a1[0], a1[1]);                  \
          o[dt] = __builtin_amdgcn_mfma_f32_16x16x32_bf16(vf, pf, o[dt],      \
                                                          0, 0, 0);           \
        }                                                                     \
      }                                                                       \
    }

    PAIR_BODY(0)

    // ---- slide the ring NOW: slots 2j,2j+1 (mod 10) were last read at pp=0.
    // ik/iv were loaded a full phase ago -> no vmcnt stall on the write. ----
    if (j < 3) {
      __syncthreads();                // all waves done reading old slots
      #pragma unroll
      for (int ii = 0; ii < 2; ++ii) {
        const int r = 32 * j + c0 + 16 * ii;
        u32x2 kw = { pk2(ik[ii][0], ik[ii][1]), pk2(ik[ii][2], ik[ii][3]) };
        *(u32x2*)(&Kl[r * 256 + ((dc * 8) ^ (c0 << 4))]) = kw;
        #pragma unroll
        for (int j4 = 0; j4 < 4; ++j4) {
          const int d = dc * 4 + j4;
          *(unsigned short*)(&Vl[d * 320 + ((r * 2) ^ SWZV(d))]) =
              __builtin_bit_cast(unsigned short, (__bf16)iv[ii][j4]);
        }
      }
    }
    // ---- issue next phase's ik/iv (used at phase j+1's slide) ----
    if (j < 2) {
      #pragma unroll
      for (int ii = 0; ii < 2; ++ii) {
        const int tk = kbase0 + 192 + 32 * j + c0 + 16 * ii;  // <= 4095
        const size_t base = (size_t)(b * S_LEN + tk) * KVROW + kvoff;
        ik[ii] = *(const f32x4*)(Kg + base);
        iv[ii] = *(const f32x4*)(Vg + base);
      }
    }
    // ---- issue next phase's Q ----
    if (j < 3) {
      const float* qp = Qg + (size_t)(b * S_LEN + n * QBLK + 32 * (j + 1)
                        + cc * 16 + l15) * (HQ * DD) + h * DD + g * 8;
      #pragma unroll
      for (int d4 = 0; d4 < 4; ++d4) {
        qa[d4] = *(const f32x4*)(qp + d4 * 32);
        qb[d4] = *(const f32x4*)(qp + d4 * 32 + 4);
      }
    }

    PAIR_BODY(1)
    PAIR_BODY(2)
    PAIR_BODY(3)
    PAIR_BODY(4)
#undef PAIR_BODY

    // ---- softmax denominator + store ----
    ls += __shfl_xor(ls, 16);
    ls += __shfl_xor(ls, 32);
    const float inv = 1.0f / ls;

    float* op = Og + (size_t)(b * S_LEN + qrow) * (HQ * DD) + h * DD + g * 4;
    #pragma unroll
    for (int dt = 0; dt < 8; ++dt) {
      f32x4 v = o[dt];
      v[0] *= inv; v[1] *= inv; v[2] *= inv; v[3] *= inv;
      *(f32x4*)(op + dt * 16) = v;
    }

    if (j < 3) __syncthreads();       // new slots visible before phase j+1
  }
}

extern "C" void kernel_launch(void* const* d_in, const int* in_sizes, int n_in,
                              void* d_out, int out_size, void* d_ws, size_t ws_size,
                              hipStream_t stream) {
  const float* Q = (const float*)d_in[0];
  const float* K = (const float*)d_in[1];
  const float* V = (const float*)d_in[2];
  float* O = (float*)d_out;
  const int B = in_sizes[0] / (S_LEN * HQ * DD);
  const int nblocks = B * HKV * (S_LEN / QBLK);   // b, hkv, n
  swa_fwd<<<dim3(nblocks), dim3(512), 0, stream>>>(Q, K, V, O);
}

// Round 19
// 87.453 us; speedup vs baseline: 1.5931x; 1.5931x over previous
//
#include <hip/hip_runtime.h>
#include <stdint.h>

#define S_LEN 4096
#define HQ 32
#define HKV 8
#define DD 128
#define QBLK 128
#define KVROW (HKV * DD)

typedef __attribute__((ext_vector_type(8)))  __bf16 bf16x8;
typedef __attribute__((ext_vector_type(2)))  __bf16 bf16x2;
typedef __attribute__((ext_vector_type(4)))  float  f32x4;
typedef __attribute__((ext_vector_type(2)))  unsigned int u32x2;
typedef __attribute__((ext_vector_type(4)))  unsigned int u32x4;

__device__ __forceinline__ unsigned int pk2(float lo, float hi2) {
  bf16x2 t = {(__bf16)lo, (__bf16)hi2};
  return __builtin_bit_cast(unsigned int, t);
}
__device__ __forceinline__ bf16x8 mk8(unsigned int w0, unsigned int w1,
                                      unsigned int w2, unsigned int w3) {
  u32x4 u = {w0, w1, w2, w3};
  return __builtin_bit_cast(bf16x8, u);
}

// V swizzle, 64-byte XOR window (V rows are 320 B).
#define SWZV(d) ((((d) & 7) ^ (((d) >> 4) & 7)) << 3)

// r19 = r17 (best-known-good, 81us) + block-uniform n==0 specialization.
// r17's per-pair guards `if(!(n==0 && tile<8))` created 10 branch regions
// per phase; scheduling regions end at branches, so the compiler could not
// interleave pair pp+1's K ds_reads under pair pp's PV tail. n is block-
// uniform: hoist to ONE top-level branch; the n!=0 hot path (31/32 blocks)
// becomes a single straight-line region per phase. r18 lesson kept: NO
// loop-carried prefetch (spills at the 128-reg budget of 4 waves/SIMD).
__global__ __launch_bounds__(512, 4)
void swa_fwd(const float* __restrict__ Qg, const float* __restrict__ Kg,
             const float* __restrict__ Vg, float* __restrict__ Og) {
  __shared__ __align__(16) unsigned char Kl[40960];  // ring [c:160][d:128] bf16
  __shared__ __align__(16) unsigned char Vl[40960];  // ring V^T [d:128][c:160]

  // XCD-aware bijective swizzle (nwg = 512, divisible by 8).
  const int nwg  = gridDim.x;
  const int bid0 = blockIdx.x;
  const int bid  = (bid0 & 7) * (nwg >> 3) + (bid0 >> 3);

  const int n    = bid & 31;
  const int hkv  = (bid >> 5) & 7;
  const int b    = bid >> 8;
  const int tid  = threadIdx.x;
  const int lane = tid & 63;
  const int wv   = tid >> 6;          // 0..7
  const int g    = lane >> 4;
  const int l15  = lane & 15;

  const int cc = wv & 1;
  const int h  = hkv * 4 + (wv >> 1);

  const int c0 = tid >> 5;            // staging row base 0..15
  const int dc = tid & 31;
  const size_t kvoff = hkv * DD + dc * 4;
  const int kbase0 = (n - 1) * QBLK;

  // ---- initial fill: ring rows 0..159 = keys kbase0..kbase0+159 ----
  #pragma unroll
  for (int i = 0; i < 10; ++i) {
    const int c = c0 + i * 16;
    int tk = kbase0 + c;
    tk = tk > 0 ? tk : 0;             // n==0 left pad; garbage lands in dead tiles
    const size_t base = (size_t)(b * S_LEN + tk) * KVROW + kvoff;
    const f32x4 xk = *(const f32x4*)(Kg + base);
    const f32x4 xv = *(const f32x4*)(Vg + base);
    u32x2 kw = { pk2(xk[0], xk[1]), pk2(xk[2], xk[3]) };
    *(u32x2*)(&Kl[c * 256 + ((dc * 8) ^ (c0 << 4))]) = kw;
    #pragma unroll
    for (int j4 = 0; j4 < 4; ++j4) {
      const int d = dc * 4 + j4;
      *(unsigned short*)(&Vl[d * 320 + ((c * 2) ^ SWZV(d))]) =
          __builtin_bit_cast(unsigned short, (__bf16)xv[j4]);
    }
  }
  __syncthreads();

  const float SC = 0.08838834764831845f * 1.44269504088896340f; // 1/sqrt(128)*log2e

#define PAIR_BODY(pp, MASKED)                                                 \
    {                                                                         \
      const int tt0 = 2 * (pp), tt1 = 2 * (pp) + 1;                           \
      if (!((MASKED) && bt + tt1 < 8)) {                                      \
        unsigned int w0 = 0, w1 = 0, w2 = 0, w3 = 0;                          \
        int rt0 = bt + tt0; rt0 = (rt0 >= 10) ? rt0 - 10 : rt0;               \
        int rt1 = bt + tt1; rt1 = (rt1 >= 10) ? rt1 - 10 : rt1;               \
        if (!((MASKED) && bt + tt0 < 8)) {                                    \
          const int c = rt0 * 16 + l15;                                       \
          f32x4 acc = {0.f, 0.f, 0.f, 0.f};                                   \
          __builtin_amdgcn_s_setprio(1);                                      \
          _Pragma("unroll")                                                   \
          for (int dcc = 0; dcc < 4; ++dcc) {                                 \
            const bf16x8 kf = *(const bf16x8*)(                               \
                &Kl[c * 256 + ((dcc * 64 + g * 16) ^ (l15 << 4))]);           \
            acc = __builtin_amdgcn_mfma_f32_16x16x32_bf16(kf, qf[dcc], acc,   \
                                                          0, 0, 0);           \
          }                                                                   \
          __builtin_amdgcn_s_setprio(0);                                      \
          float p[4];                                                         \
          _Pragma("unroll")                                                   \
          for (int r = 0; r < 4; ++r) {                                       \
            const int g4r = g * 4 + r;                                        \
            const float e = __builtin_amdgcn_exp2f(acc[r] * SC);              \
            bool valid = true;                                                \
            if ((pp) == 0) valid = (g4r > l15);                               \
            if ((pp) == 4) valid = (g4r <= l15);                              \
            p[r] = valid ? e : 0.f;                                           \
            ls += p[r];                                                       \
          }                                                                   \
          w0 = pk2(p[0], p[1]);                                               \
          w1 = pk2(p[2], p[3]);                                               \
        }                                                                     \
        if ((pp) < 4 && !((MASKED) && bt + tt1 < 8)) {                        \
          const int c = rt1 * 16 + l15;                                       \
          f32x4 acc = {0.f, 0.f, 0.f, 0.f};                                   \
          __builtin_amdgcn_s_setprio(1);                                      \
          _Pragma("unroll")                                                   \
          for (int dcc = 0; dcc < 4; ++dcc) {                                 \
            const bf16x8 kf = *(const bf16x8*)(                               \
                &Kl[c * 256 + ((dcc * 64 + g * 16) ^ (l15 << 4))]);           \
            acc = __builtin_amdgcn_mfma_f32_16x16x32_bf16(kf, qf[dcc], acc,   \
                                                          0, 0, 0);           \
          }                                                                   \
          __builtin_amdgcn_s_setprio(0);                                      \
          float p0 = __builtin_amdgcn_exp2f(acc[0] * SC);                     \
          float p1 = __builtin_amdgcn_exp2f(acc[1] * SC);                     \
          float p2 = __builtin_amdgcn_exp2f(acc[2] * SC);                     \
          float p3 = __builtin_amdgcn_exp2f(acc[3] * SC);                     \
          ls += p0 + p1 + p2 + p3;                                            \
          w2 = pk2(p0, p1);                                                   \
          w3 = pk2(p2, p3);                                                   \
        }                                                                     \
        const bf16x8 pf = mk8(w0, w1, w2, w3);                                \
        const int ck0 = (rt0 * 16 + g * 4) * 2;                               \
        const int ck1 = ((pp) < 4) ? (rt1 * 16 + g * 4) * 2 : ck0;            \
        __builtin_amdgcn_s_setprio(1);                                        \
        _Pragma("unroll")                                                     \
        for (int dt = 0; dt < 8; ++dt) {                                      \
          const int d  = dt * 16 + l15;                                       \
          const int rb = d * 320;                                             \
          const int sz = SWZV(d);                                             \
          const u32x2 a0 = *(const u32x2*)(&Vl[rb + (ck0 ^ sz)]);             \
          const u32x2 a1 = *(const u32x2*)(&Vl[rb + (ck1 ^ sz)]);             \
          const bf16x8 vf = mk8(a0[0], a0[1], a1[0], a1[1]);                  \
          o[dt] = __builtin_amdgcn_mfma_f32_16x16x32_bf16(vf, pf, o[dt],      \
                                                          0, 0, 0);           \
        }                                                                     \
        __builtin_amdgcn_s_setprio(0);                                        \
      }                                                                       \
    }

#define PHASE_LOOP(MASKED)                                                    \
  _Pragma("unroll 1")                                                         \
  for (int j = 0; j < 4; ++j) {                                               \
    const int qrow = n * QBLK + 32 * j + cc * 16 + l15;                       \
    const float* qp = Qg + (size_t)(b * S_LEN + qrow) * (HQ * DD)             \
                      + h * DD + g * 8;                                       \
    f32x4 qa[4], qb[4];                                                       \
    _Pragma("unroll")                                                         \
    for (int d4 = 0; d4 < 4; ++d4) {                                          \
      qa[d4] = *(const f32x4*)(qp + d4 * 32);                                 \
      qb[d4] = *(const f32x4*)(qp + d4 * 32 + 4);                             \
    }                                                                         \
    f32x4 ik[2], iv[2];                                                       \
    if (j < 3) {                                                              \
      _Pragma("unroll")                                                       \
      for (int ii = 0; ii < 2; ++ii) {                                        \
        const int tk = kbase0 + 160 + 32 * j + c0 + 16 * ii;                  \
        const size_t base = (size_t)(b * S_LEN + tk) * KVROW + kvoff;         \
        ik[ii] = *(const f32x4*)(Kg + base);                                  \
        iv[ii] = *(const f32x4*)(Vg + base);                                  \
      }                                                                       \
    }                                                                         \
    bf16x8 qf[4];                                                             \
    _Pragma("unroll")                                                         \
    for (int d4 = 0; d4 < 4; ++d4)                                            \
      qf[d4] = mk8(pk2(qa[d4][0], qa[d4][1]), pk2(qa[d4][2], qa[d4][3]),      \
                   pk2(qb[d4][0], qb[d4][1]), pk2(qb[d4][2], qb[d4][3]));     \
    f32x4 o[8];                                                               \
    _Pragma("unroll")                                                         \
    for (int dt = 0; dt < 8; ++dt) o[dt] = (f32x4){0.f, 0.f, 0.f, 0.f};       \
    float ls = 0.f;                                                           \
    const int bt = 2 * j + cc;                                                \
    PAIR_BODY(0, MASKED)                                                      \
    PAIR_BODY(1, MASKED)                                                      \
    PAIR_BODY(2, MASKED)                                                      \
    PAIR_BODY(3, MASKED)                                                      \
    PAIR_BODY(4, MASKED)                                                      \
    ls += __shfl_xor(ls, 16);                                                 \
    ls += __shfl_xor(ls, 32);                                                 \
    const float inv = 1.0f / ls;                                              \
    float* op = Og + (size_t)(b * S_LEN + qrow) * (HQ * DD) + h * DD + g * 4; \
    _Pragma("unroll")                                                         \
    for (int dt = 0; dt < 8; ++dt) {                                          \
      f32x4 v = o[dt];                                                        \
      v[0] *= inv; v[1] *= inv; v[2] *= inv; v[3] *= inv;                     \
      *(f32x4*)(op + dt * 16) = v;                                            \
    }                                                                         \
    if (j < 3) {                                                              \
      __syncthreads();                                                        \
      _Pragma("unroll")                                                       \
      for (int ii = 0; ii < 2; ++ii) {                                        \
        const int r = 32 * j + c0 + 16 * ii;                                  \
        u32x2 kw = { pk2(ik[ii][0], ik[ii][1]), pk2(ik[ii][2], ik[ii][3]) };  \
        *(u32x2*)(&Kl[r * 256 + ((dc * 8) ^ (c0 << 4))]) = kw;                \
        _Pragma("unroll")                                                     \
        for (int j4 = 0; j4 < 4; ++j4) {                                      \
          const int d = dc * 4 + j4;                                          \
          *(unsigned short*)(&Vl[d * 320 + ((r * 2) ^ SWZV(d))]) =            \
              __builtin_bit_cast(unsigned short, (__bf16)iv[ii][j4]);         \
        }                                                                     \
      }                                                                       \
      __syncthreads();                                                        \
    }                                                                         \
  }

  if (n == 0) {
    PHASE_LOOP(1)     // guarded path: left-pad tiles masked out
  } else {
    PHASE_LOOP(0)     // hot path: guard-free straight-line pairs
  }
#undef PHASE_LOOP
#undef PAIR_BODY
}

extern "C" void kernel_launch(void* const* d_in, const int* in_sizes, int n_in,
                              void* d_out, int out_size, void* d_ws, size_t ws_size,
                              hipStream_t stream) {
  const float* Q = (const float*)d_in[0];
  const float* K = (const float*)d_in[1];
  const float* V = (const float*)d_in[2];
  float* O = (float*)d_out;
  const int B = in_sizes[0] / (S_LEN * HQ * DD);
  const int nblocks = B * HKV * (S_LEN / QBLK);   // b, hkv, n
  swa_fwd<<<dim3(nblocks), dim3(512), 0, stream>>>(Q, K, V, O);
}

// Round 20
// 85.685 us; speedup vs baseline: 1.6260x; 1.0206x over previous
//
#include <hip/hip_runtime.h>
#include <stdint.h>

#define S_LEN 4096
#define HQ 32
#define HKV 8
#define DD 128
#define QBLK 128
#define KVROW (HKV * DD)

typedef __attribute__((ext_vector_type(8)))  __bf16 bf16x8;
typedef __attribute__((ext_vector_type(2)))  __bf16 bf16x2;
typedef __attribute__((ext_vector_type(4)))  float  f32x4;
typedef __attribute__((ext_vector_type(2)))  unsigned int u32x2;
typedef __attribute__((ext_vector_type(4)))  unsigned int u32x4;

__device__ __forceinline__ unsigned int pk2(float lo, float hi2) {
  bf16x2 t = {(__bf16)lo, (__bf16)hi2};
  return __builtin_bit_cast(unsigned int, t);
}
__device__ __forceinline__ bf16x8 mk8(unsigned int w0, unsigned int w1,
                                      unsigned int w2, unsigned int w3) {
  u32x4 u = {w0, w1, w2, w3};
  return __builtin_bit_cast(bf16x8, u);
}

// V swizzle, 64-byte XOR window (V rows are 320 B).
#define SWZV(d) ((((d) & 7) ^ (((d) >> 4) & 7)) << 3)

// r20 = r17 (best-known-good, 81us; r19's n==0 hoist reverted) with ONE
// register-neutral edit: the ring slide moves from phase end (sync; write;
// sync back-to-back -- all 8 waves queue twice with zero work between) to
// right after PAIR 0. Written slots (2j,2j+1 mod 10) are read only at pp=0
// this phase (pairs 1-4 read bt+2..bt+9, excluding them; pp=4 uses tt0 only)
// and next at pp>=3 of phase j+1, so: barrier#1 after pair 0 (waves still
// have pairs 1-4 + store ahead), write immediately (ik/iv issued at phase
// top, ~1 pair of latency cover, L2-resident), barrier#2 stays at phase end
// -- ~2000 cyc of compute now sits between the two barriers. r18's slide
// placement WITHOUT r18's loop-carried registers (those spilled).
__global__ __launch_bounds__(512, 4)
void swa_fwd(const float* __restrict__ Qg, const float* __restrict__ Kg,
             const float* __restrict__ Vg, float* __restrict__ Og) {
  __shared__ __align__(16) unsigned char Kl[40960];  // ring [c:160][d:128] bf16
  __shared__ __align__(16) unsigned char Vl[40960];  // ring V^T [d:128][c:160]

  // XCD-aware bijective swizzle (nwg = 512, divisible by 8).
  const int nwg  = gridDim.x;
  const int bid0 = blockIdx.x;
  const int bid  = (bid0 & 7) * (nwg >> 3) + (bid0 >> 3);

  const int n    = bid & 31;
  const int hkv  = (bid >> 5) & 7;
  const int b    = bid >> 8;
  const int tid  = threadIdx.x;
  const int lane = tid & 63;
  const int wv   = tid >> 6;          // 0..7
  const int g    = lane >> 4;
  const int l15  = lane & 15;

  const int cc = wv & 1;
  const int h  = hkv * 4 + (wv >> 1);

  const int c0 = tid >> 5;            // staging row base 0..15
  const int dc = tid & 31;
  const size_t kvoff = hkv * DD + dc * 4;
  const int kbase0 = (n - 1) * QBLK;

  // ---- initial fill: ring rows 0..159 = keys kbase0..kbase0+159 ----
  #pragma unroll
  for (int i = 0; i < 10; ++i) {
    const int c = c0 + i * 16;
    int tk = kbase0 + c;
    tk = tk > 0 ? tk : 0;             // n==0 left pad; garbage lands in dead tiles
    const size_t base = (size_t)(b * S_LEN + tk) * KVROW + kvoff;
    const f32x4 xk = *(const f32x4*)(Kg + base);
    const f32x4 xv = *(const f32x4*)(Vg + base);
    u32x2 kw = { pk2(xk[0], xk[1]), pk2(xk[2], xk[3]) };
    *(u32x2*)(&Kl[c * 256 + ((dc * 8) ^ (c0 << 4))]) = kw;
    #pragma unroll
    for (int j4 = 0; j4 < 4; ++j4) {
      const int d = dc * 4 + j4;
      *(unsigned short*)(&Vl[d * 320 + ((c * 2) ^ SWZV(d))]) =
          __builtin_bit_cast(unsigned short, (__bf16)xv[j4]);
    }
  }
  __syncthreads();

  const float SC = 0.08838834764831845f * 1.44269504088896340f; // 1/sqrt(128)*log2e

  #pragma unroll 1
  for (int j = 0; j < 4; ++j) {
    // ---- issue this phase's Q loads ----
    const int qrow = n * QBLK + 32 * j + cc * 16 + l15;
    const float* qp = Qg + (size_t)(b * S_LEN + qrow) * (HQ * DD) + h * DD + g * 8;
    f32x4 qa[4], qb[4];
    #pragma unroll
    for (int d4 = 0; d4 < 4; ++d4) {
      qa[d4] = *(const f32x4*)(qp + d4 * 32);
      qb[d4] = *(const f32x4*)(qp + d4 * 32 + 4);
    }

    // ---- issue the +32-key incremental loads (consumed after pair 0) ----
    f32x4 ik[2], iv[2];
    if (j < 3) {
      #pragma unroll
      for (int ii = 0; ii < 2; ++ii) {   // keys >= 32 always -> no clamp
        const int tk = kbase0 + 160 + 32 * j + c0 + 16 * ii;
        const size_t base = (size_t)(b * S_LEN + tk) * KVROW + kvoff;
        ik[ii] = *(const f32x4*)(Kg + base);
        iv[ii] = *(const f32x4*)(Vg + base);
      }
    }

    // ---- convert Q ----
    bf16x8 qf[4];
    #pragma unroll
    for (int d4 = 0; d4 < 4; ++d4)
      qf[d4] = mk8(pk2(qa[d4][0], qa[d4][1]), pk2(qa[d4][2], qa[d4][3]),
                   pk2(qb[d4][0], qb[d4][1]), pk2(qb[d4][2], qb[d4][3]));

    f32x4 o[8];
    #pragma unroll
    for (int dt = 0; dt < 8; ++dt) o[dt] = (f32x4){0.f, 0.f, 0.f, 0.f};
    float ls = 0.f;

    const int bt = 2 * j + cc;

#define PAIR_BODY(pp)                                                         \
    {                                                                         \
      const int tt0 = 2 * (pp), tt1 = 2 * (pp) + 1;                           \
      if (!(n == 0 && bt + tt1 < 8)) {                                        \
        unsigned int w0 = 0, w1 = 0, w2 = 0, w3 = 0;                          \
        int rt0 = bt + tt0; rt0 = (rt0 >= 10) ? rt0 - 10 : rt0;               \
        int rt1 = bt + tt1; rt1 = (rt1 >= 10) ? rt1 - 10 : rt1;               \
        if (!(n == 0 && bt + tt0 < 8)) {                                      \
          const int c = rt0 * 16 + l15;                                       \
          f32x4 acc = {0.f, 0.f, 0.f, 0.f};                                   \
          __builtin_amdgcn_s_setprio(1);                                      \
          _Pragma("unroll")                                                   \
          for (int dcc = 0; dcc < 4; ++dcc) {                                 \
            const bf16x8 kf = *(const bf16x8*)(                               \
                &Kl[c * 256 + ((dcc * 64 + g * 16) ^ (l15 << 4))]);           \
            acc = __builtin_amdgcn_mfma_f32_16x16x32_bf16(kf, qf[dcc], acc,   \
                                                          0, 0, 0);           \
          }                                                                   \
          __builtin_amdgcn_s_setprio(0);                                      \
          float p[4];                                                         \
          _Pragma("unroll")                                                   \
          for (int r = 0; r < 4; ++r) {                                       \
            const int g4r = g * 4 + r;                                        \
            const float e = __builtin_amdgcn_exp2f(acc[r] * SC);              \
            bool valid = true;                                                \
            if ((pp) == 0) valid = (g4r > l15);                               \
            if ((pp) == 4) valid = (g4r <= l15);                              \
            p[r] = valid ? e : 0.f;                                           \
            ls += p[r];                                                       \
          }                                                                   \
          w0 = pk2(p[0], p[1]);                                               \
          w1 = pk2(p[2], p[3]);                                               \
        }                                                                     \
        if ((pp) < 4 && !(n == 0 && bt + tt1 < 8)) {                          \
          const int c = rt1 * 16 + l15;                                       \
          f32x4 acc = {0.f, 0.f, 0.f, 0.f};                                   \
          __builtin_amdgcn_s_setprio(1);                                      \
          _Pragma("unroll")                                                   \
          for (int dcc = 0; dcc < 4; ++dcc) {                                 \
            const bf16x8 kf = *(const bf16x8*)(                               \
                &Kl[c * 256 + ((dcc * 64 + g * 16) ^ (l15 << 4))]);           \
            acc = __builtin_amdgcn_mfma_f32_16x16x32_bf16(kf, qf[dcc], acc,   \
                                                          0, 0, 0);           \
          }                                                                   \
          __builtin_amdgcn_s_setprio(0);                                      \
          float p0 = __builtin_amdgcn_exp2f(acc[0] * SC);                     \
          float p1 = __builtin_amdgcn_exp2f(acc[1] * SC);                     \
          float p2 = __builtin_amdgcn_exp2f(acc[2] * SC);                     \
          float p3 = __builtin_amdgcn_exp2f(acc[3] * SC);                     \
          ls += p0 + p1 + p2 + p3;                                            \
          w2 = pk2(p0, p1);                                                   \
          w3 = pk2(p2, p3);                                                   \
        }                                                                     \
        const bf16x8 pf = mk8(w0, w1, w2, w3);                                \
        const int ck0 = (rt0 * 16 + g * 4) * 2;                               \
        const int ck1 = ((pp) < 4) ? (rt1 * 16 + g * 4) * 2 : ck0;            \
        __builtin_amdgcn_s_setprio(1);                                        \
        _Pragma("unroll")                                                     \
        for (int dt = 0; dt < 8; ++dt) {                                      \
          const int d  = dt * 16 + l15;                                       \
          const int rb = d * 320;                                             \
          const int sz = SWZV(d);                                             \
          const u32x2 a0 = *(const u32x2*)(&Vl[rb + (ck0 ^ sz)]);             \
          const u32x2 a1 = *(const u32x2*)(&Vl[rb + (ck1 ^ sz)]);             \
          const bf16x8 vf = mk8(a0[0], a0[1], a1[0], a1[1]);                  \
          o[dt] = __builtin_amdgcn_mfma_f32_16x16x32_bf16(vf, pf, o[dt],      \
                                                          0, 0, 0);           \
        }                                                                     \
        __builtin_amdgcn_s_setprio(0);                                        \
      }                                                                       \
    }

    PAIR_BODY(0)

    // ---- slide the ring EARLY: slots 2j,2j+1 (mod 10) had their last read
    // at pp=0 (pairs 1-4 read bt+2..bt+9, excluding them). barrier#1 lands
    // while pairs 1-4 + store still lie ahead; barrier#2 is at phase end. ----
    if (j < 3) {
      __syncthreads();                // all waves done with pp=0 reads
      #pragma unroll
      for (int ii = 0; ii < 2; ++ii) {
        const int r = 32 * j + c0 + 16 * ii;
        u32x2 kw = { pk2(ik[ii][0], ik[ii][1]), pk2(ik[ii][2], ik[ii][3]) };
        *(u32x2*)(&Kl[r * 256 + ((dc * 8) ^ (c0 << 4))]) = kw;
        #pragma unroll
        for (int j4 = 0; j4 < 4; ++j4) {
          const int d = dc * 4 + j4;
          *(unsigned short*)(&Vl[d * 320 + ((r * 2) ^ SWZV(d))]) =
              __builtin_bit_cast(unsigned short, (__bf16)iv[ii][j4]);
        }
      }
    }

    PAIR_BODY(1)
    PAIR_BODY(2)
    PAIR_BODY(3)
    PAIR_BODY(4)
#undef PAIR_BODY

    // ---- softmax denominator + store ----
    ls += __shfl_xor(ls, 16);
    ls += __shfl_xor(ls, 32);
    const float inv = 1.0f / ls;

    float* op = Og + (size_t)(b * S_LEN + qrow) * (HQ * DD) + h * DD + g * 4;
    #pragma unroll
    for (int dt = 0; dt < 8; ++dt) {
      f32x4 v = o[dt];
      v[0] *= inv; v[1] *= inv; v[2] *= inv; v[3] *= inv;
      *(f32x4*)(op + dt * 16) = v;
    }

    if (j < 3) __syncthreads();       // new slots visible before phase j+1
  }
}

extern "C" void kernel_launch(void* const* d_in, const int* in_sizes, int n_in,
                              void* d_out, int out_size, void* d_ws, size_t ws_size,
                              hipStream_t stream) {
  const float* Q = (const float*)d_in[0];
  const float* K = (const float*)d_in[1];
  const float* V = (const float*)d_in[2];
  float* O = (float*)d_out;
  const int B = in_sizes[0] / (S_LEN * HQ * DD);
  const int nblocks = B * HKV * (S_LEN / QBLK);   // b, hkv, n
  swa_fwd<<<dim3(nblocks), dim3(512), 0, stream>>>(Q, K, V, O);
}

// Round 21
// 78.483 us; speedup vs baseline: 1.7752x; 1.0918x over previous
//
#include <hip/hip_runtime.h>
#include <stdint.h>

#define S_LEN 4096
#define HQ 32
#define HKV 8
#define DD 128
#define QBLK 128
#define KVROW (HKV * DD)

typedef __attribute__((ext_vector_type(8)))  __bf16 bf16x8;
typedef __attribute__((ext_vector_type(2)))  __bf16 bf16x2;
typedef __attribute__((ext_vector_type(4)))  float  f32x4;
typedef __attribute__((ext_vector_type(2)))  unsigned int u32x2;
typedef __attribute__((ext_vector_type(4)))  unsigned int u32x4;

// RNE f32x2 -> packed bf16x2 (compiler emits v_cvt_pk_bf16_f32).
__device__ __forceinline__ unsigned int pk2(float lo, float hi2) {
  bf16x2 t = {(__bf16)lo, (__bf16)hi2};
  return __builtin_bit_cast(unsigned int, t);
}
__device__ __forceinline__ bf16x8 mk8(unsigned int w0, unsigned int w1,
                                      unsigned int w2, unsigned int w3) {
  u32x4 u = {w0, w1, w2, w3};
  return __builtin_bit_cast(bf16x8, u);
}

// V swizzle, 64-byte XOR window (V rows are 320 B; (c*2)|56 <= 318 < 320).
#define SWZV(d) ((((d) & 7) ^ (((d) >> 4) & 7)) << 3)

// FINAL = r17 (best measured: 81.1us). RING-BUFFER WINDOW: one block per
// (b,hkv,n) processes all four 32-row q-sub-blocks, sliding a 160-key K/V
// ring (mod 10 tiles) by 32 keys per phase. Rounds 18-20 established that
// every deeper-pipelining variant (loop-carried prefetch, guard hoisting,
// early slide) is null or negative at the 128-unified-reg budget that
// 4 waves/SIMD imposes; traffic is already minimal (WRITE at ideal).
__global__ __launch_bounds__(512, 4)
void swa_fwd(const float* __restrict__ Qg, const float* __restrict__ Kg,
             const float* __restrict__ Vg, float* __restrict__ Og) {
  __shared__ __align__(16) unsigned char Kl[40960];  // ring [c:160][d:128] bf16
  __shared__ __align__(16) unsigned char Vl[40960];  // ring V^T [d:128][c:160]

  // XCD-aware bijective swizzle (nwg = 512, divisible by 8): adjacent n
  // windows overlap 128 keys -> same-XCD L2 hits.
  const int nwg  = gridDim.x;
  const int bid0 = blockIdx.x;
  const int bid  = (bid0 & 7) * (nwg >> 3) + (bid0 >> 3);

  const int n    = bid & 31;          // q-block index
  const int hkv  = (bid >> 5) & 7;
  const int b    = bid >> 8;
  const int tid  = threadIdx.x;
  const int lane = tid & 63;
  const int wv   = tid >> 6;          // 0..7
  const int g    = lane >> 4;         // 16-lane group 0..3
  const int l15  = lane & 15;

  // 8 waves = 4 heads x 2 16-row chunks; each wave does one unit per phase.
  const int cc = wv & 1;
  const int h  = hkv * 4 + (wv >> 1);

  const int c0 = tid >> 5;            // staging row base 0..15
  const int dc = tid & 31;            // float4 index within d
  const size_t kvoff = hkv * DD + dc * 4;
  const int kbase0 = (n - 1) * QBLK;

  // ---- initial fill: ring rows 0..159 = keys kbase0..kbase0+159 ----
  #pragma unroll
  for (int i = 0; i < 10; ++i) {
    const int c = c0 + i * 16;
    int tk = kbase0 + c;
    tk = tk > 0 ? tk : 0;             // branchless clamp (n==0 left pad;
                                      // garbage rows land in masked-dead tiles)
    const size_t base = (size_t)(b * S_LEN + tk) * KVROW + kvoff;
    const f32x4 xk = *(const f32x4*)(Kg + base);
    const f32x4 xv = *(const f32x4*)(Vg + base);
    u32x2 kw = { pk2(xk[0], xk[1]), pk2(xk[2], xk[3]) };
    *(u32x2*)(&Kl[c * 256 + ((dc * 8) ^ (c0 << 4))]) = kw;
    #pragma unroll
    for (int j4 = 0; j4 < 4; ++j4) {
      const int d = dc * 4 + j4;
      *(unsigned short*)(&Vl[d * 320 + ((c * 2) ^ SWZV(d))]) =
          __builtin_bit_cast(unsigned short, (__bf16)xv[j4]);
    }
  }
  __syncthreads();

  const float SC = 0.08838834764831845f * 1.44269504088896340f; // 1/sqrt(128)*log2e

  #pragma unroll 1
  for (int j = 0; j < 4; ++j) {
    // ---- issue this phase's Q loads ----
    const int qrow = n * QBLK + 32 * j + cc * 16 + l15;
    const float* qp = Qg + (size_t)(b * S_LEN + qrow) * (HQ * DD) + h * DD + g * 8;
    f32x4 qa[4], qb[4];
    #pragma unroll
    for (int d4 = 0; d4 < 4; ++d4) {
      qa[d4] = *(const f32x4*)(qp + d4 * 32);
      qb[d4] = *(const f32x4*)(qp + d4 * 32 + 4);
    }

    // ---- issue the +32-key incremental loads (fly under this compute) ----
    // keys kbase0+160+32j+rr >= 32 always (even n==0) -> no clamp needed.
    f32x4 ik[2], iv[2];
    if (j < 3) {
      #pragma unroll
      for (int ii = 0; ii < 2; ++ii) {
        const int tk = kbase0 + 160 + 32 * j + c0 + 16 * ii;
        const size_t base = (size_t)(b * S_LEN + tk) * KVROW + kvoff;
        ik[ii] = *(const f32x4*)(Kg + base);
        iv[ii] = *(const f32x4*)(Vg + base);
      }
    }

    // ---- convert Q ----
    bf16x8 qf[4];
    #pragma unroll
    for (int d4 = 0; d4 < 4; ++d4)
      qf[d4] = mk8(pk2(qa[d4][0], qa[d4][1]), pk2(qa[d4][2], qa[d4][3]),
                   pk2(qb[d4][0], qb[d4][1]), pk2(qb[d4][2], qb[d4][3]));

    f32x4 o[8];
    #pragma unroll
    for (int dt = 0; dt < 8; ++dt) o[dt] = (f32x4){0.f, 0.f, 0.f, 0.f};
    float ls = 0.f;

    const int bt = 2 * j + cc;        // global tile base (= ring base pre-mod)

#define PAIR_BODY(pp)                                                         \
    {                                                                         \
      const int tt0 = 2 * (pp), tt1 = 2 * (pp) + 1;                           \
      if (!(n == 0 && bt + tt1 < 8)) {                                        \
        unsigned int w0 = 0, w1 = 0, w2 = 0, w3 = 0;                          \
        int rt0 = bt + tt0; rt0 = (rt0 >= 10) ? rt0 - 10 : rt0;               \
        int rt1 = bt + tt1; rt1 = (rt1 >= 10) ? rt1 - 10 : rt1;               \
        if (!(n == 0 && bt + tt0 < 8)) {                                      \
          const int c = rt0 * 16 + l15;                                       \
          f32x4 acc = {0.f, 0.f, 0.f, 0.f};                                   \
          __builtin_amdgcn_s_setprio(1);                                      \
          _Pragma("unroll")                                                   \
          for (int dcc = 0; dcc < 4; ++dcc) {                                 \
            const bf16x8 kf = *(const bf16x8*)(                               \
                &Kl[c * 256 + ((dcc * 64 + g * 16) ^ (l15 << 4))]);           \
            acc = __builtin_amdgcn_mfma_f32_16x16x32_bf16(kf, qf[dcc], acc,   \
                                                          0, 0, 0);           \
          }                                                                   \
          __builtin_amdgcn_s_setprio(0);                                      \
          float p[4];                                                         \
          _Pragma("unroll")                                                   \
          for (int r = 0; r < 4; ++r) {                                       \
            const int g4r = g * 4 + r;                                        \
            const float e = __builtin_amdgcn_exp2f(acc[r] * SC);              \
            bool valid = true;                                                \
            if ((pp) == 0) valid = (g4r > l15);                               \
            if ((pp) == 4) valid = (g4r <= l15);                              \
            p[r] = valid ? e : 0.f;                                           \
            ls += p[r];                                                       \
          }                                                                   \
          w0 = pk2(p[0], p[1]);                                               \
          w1 = pk2(p[2], p[3]);                                               \
        }                                                                     \
        if ((pp) < 4 && !(n == 0 && bt + tt1 < 8)) {                          \
          const int c = rt1 * 16 + l15;                                       \
          f32x4 acc = {0.f, 0.f, 0.f, 0.f};                                   \
          __builtin_amdgcn_s_setprio(1);                                      \
          _Pragma("unroll")                                                   \
          for (int dcc = 0; dcc < 4; ++dcc) {                                 \
            const bf16x8 kf = *(const bf16x8*)(                               \
                &Kl[c * 256 + ((dcc * 64 + g * 16) ^ (l15 << 4))]);           \
            acc = __builtin_amdgcn_mfma_f32_16x16x32_bf16(kf, qf[dcc], acc,   \
                                                          0, 0, 0);           \
          }                                                                   \
          __builtin_amdgcn_s_setprio(0);                                      \
          float p0 = __builtin_amdgcn_exp2f(acc[0] * SC);                     \
          float p1 = __builtin_amdgcn_exp2f(acc[1] * SC);                     \
          float p2 = __builtin_amdgcn_exp2f(acc[2] * SC);                     \
          float p3 = __builtin_amdgcn_exp2f(acc[3] * SC);                     \
          ls += p0 + p1 + p2 + p3;                                            \
          w2 = pk2(p0, p1);                                                   \
          w3 = pk2(p2, p3);                                                   \
        }                                                                     \
        const bf16x8 pf = mk8(w0, w1, w2, w3);                                \
        const int ck0 = (rt0 * 16 + g * 4) * 2;                               \
        const int ck1 = ((pp) < 4) ? (rt1 * 16 + g * 4) * 2 : ck0;            \
        __builtin_amdgcn_s_setprio(1);                                        \
        _Pragma("unroll")                                                     \
        for (int dt = 0; dt < 8; ++dt) {                                      \
          const int d  = dt * 16 + l15;                                       \
          const int rb = d * 320;                                             \
          const int sz = SWZV(d);                                             \
          const u32x2 a0 = *(const u32x2*)(&Vl[rb + (ck0 ^ sz)]);             \
          const u32x2 a1 = *(const u32x2*)(&Vl[rb + (ck1 ^ sz)]);             \
          const bf16x8 vf = mk8(a0[0], a0[1], a1[0], a1[1]);                  \
          o[dt] = __builtin_amdgcn_mfma_f32_16x16x32_bf16(vf, pf, o[dt],      \
                                                          0, 0, 0);           \
        }                                                                     \
        __builtin_amdgcn_s_setprio(0);                                        \
      }                                                                       \
    }

    PAIR_BODY(0)
    PAIR_BODY(1)
    PAIR_BODY(2)
    PAIR_BODY(3)
    PAIR_BODY(4)
#undef PAIR_BODY

    // ---- softmax denominator + store (all outputs of this lane share q) ----
    ls += __shfl_xor(ls, 16);
    ls += __shfl_xor(ls, 32);
    const float inv = 1.0f / ls;

    float* op = Og + (size_t)(b * S_LEN + qrow) * (HQ * DD) + h * DD + g * 4;
    #pragma unroll
    for (int dt = 0; dt < 8; ++dt) {
      f32x4 v = o[dt];
      v[0] *= inv; v[1] *= inv; v[2] *= inv; v[3] *= inv;
      *(f32x4*)(op + dt * 16) = v;
    }

    // ---- slide the ring: overwrite tiles 2j,2j+1 with keys +160..+191 ----
    if (j < 3) {
      __syncthreads();                // all reads of the old tiles done
      #pragma unroll
      for (int ii = 0; ii < 2; ++ii) {
        const int r = 32 * j + c0 + 16 * ii;       // ring row (r & 15 == c0)
        u32x2 kw = { pk2(ik[ii][0], ik[ii][1]), pk2(ik[ii][2], ik[ii][3]) };
        *(u32x2*)(&Kl[r * 256 + ((dc * 8) ^ (c0 << 4))]) = kw;
        #pragma unroll
        for (int j4 = 0; j4 < 4; ++j4) {
          const int d = dc * 4 + j4;
          *(unsigned short*)(&Vl[d * 320 + ((r * 2) ^ SWZV(d))]) =
              __builtin_bit_cast(unsigned short, (__bf16)iv[ii][j4]);
        }
      }
      __syncthreads();                // new tiles visible to all waves
    }
  }
}

extern "C" void kernel_launch(void* const* d_in, const int* in_sizes, int n_in,
                              void* d_out, int out_size, void* d_ws, size_t ws_size,
                              hipStream_t stream) {
  const float* Q = (const float*)d_in[0];
  const float* K = (const float*)d_in[1];
  const float* V = (const float*)d_in[2];
  float* O = (float*)d_out;
  const int B = in_sizes[0] / (S_LEN * HQ * DD);
  const int nblocks = B * HKV * (S_LEN / QBLK);   // b, hkv, n
  swa_fwd<<<dim3(nblocks), dim3(512), 0, stream>>>(Q, K, V, O);
}